// Round 1
// baseline (332.566 us; speedup 1.0000x reference)
//
#include <hip/hip_runtime.h>
#include <stdint.h>

// Problem constants
#define TOKS   262144      // B*S = 32*8192
#define NGRP   16384       // B*G = 32*512
#define EMB    1024
#define HD     64

using bf16x8 = __attribute__((ext_vector_type(8))) short;   // 8 bf16 (4 VGPRs) MFMA operand
using f32x4  = __attribute__((ext_vector_type(4))) float;   // MFMA accumulator

__device__ __forceinline__ float bf2f(unsigned short u) {
    unsigned v = ((unsigned)u) << 16;
    return __builtin_bit_cast(float, v);
}
__device__ __forceinline__ unsigned short f2bf(float f) {
    unsigned x = __builtin_bit_cast(unsigned, f);
    unsigned r = (x + 0x7fffu + ((x >> 16) & 1u)) >> 16;   // RNE
    return (unsigned short)r;
}
__device__ __forceinline__ unsigned pack2(float a, float b) {
    return (unsigned)f2bf(a) | ((unsigned)f2bf(b) << 16);
}

// ---------------------------------------------------------------------------
// K0: convert Wo (fp32 [1024][1024]) -> bf16
// ---------------------------------------------------------------------------
__global__ __launch_bounds__(256) void k_cvt_wo(const float* __restrict__ wo,
                                                unsigned short* __restrict__ out) {
    int idx = (blockIdx.x * 256 + threadIdx.x) * 4;
    float4 v = *(const float4*)(wo + idx);
    uint2 p;
    p.x = pack2(v.x, v.y);
    p.y = pack2(v.z, v.w);
    *(uint2*)(out + idx) = p;
}

// ---------------------------------------------------------------------------
// K1a: QKV projection, fp32 compute -> bf16 qkv[tok][192] (Q|K|V)
// Block: 256 threads, 64 tokens. W stored transposed in LDS: Wt[m][k][j].
// Thread computes 8 tokens x 6 cols (48 accs): 14 LDS reads / 48 FMAs per k.
// ---------------------------------------------------------------------------
__global__ __launch_bounds__(256) void k_qkv(const float* __restrict__ x,
                                             const float* __restrict__ wq,
                                             const float* __restrict__ wk,
                                             const float* __restrict__ wv,
                                             unsigned short* __restrict__ qkv) {
    __shared__ float Wt[3 * 64 * 64];   // [m][k][j] = W_m[j][k]
    __shared__ float Xs[64 * 64];       // [i][k]
    int t = threadIdx.x;
    int tb = blockIdx.x * 64;

    // Load weights transposed (coalesced global float4 read, scalar LDS writes)
    #pragma unroll
    for (int m = 0; m < 3; ++m) {
        const float* W = (m == 0) ? wq : ((m == 1) ? wk : wv);
        #pragma unroll
        for (int q = 0; q < 4; ++q) {
            int linear = q * 256 + t;            // float4 index in 64x64
            int j  = linear >> 4;
            int k0 = (linear & 15) * 4;
            float4 v = *(const float4*)(W + j * 64 + k0);
            Wt[m * 4096 + (k0 + 0) * 64 + j] = v.x;
            Wt[m * 4096 + (k0 + 1) * 64 + j] = v.y;
            Wt[m * 4096 + (k0 + 2) * 64 + j] = v.z;
            Wt[m * 4096 + (k0 + 3) * 64 + j] = v.w;
        }
    }
    // Load X tile (contiguous)
    #pragma unroll
    for (int q = 0; q < 4; ++q) {
        int linear = q * 256 + t;
        *(float4*)(Xs + linear * 4) = *(const float4*)(x + tb * 64 + linear * 4);
    }
    __syncthreads();

    int i0 = (t >> 5) * 8;      // token octet
    int j0 = (t & 31) * 6;      // 6 output cols in [0,192)
    int widx[6];
    #pragma unroll
    for (int jj = 0; jj < 6; ++jj) {
        int j = j0 + jj;
        widx[jj] = (j >> 6) * 4096 + (j & 63);
    }
    float acc[8][6];
    #pragma unroll
    for (int ii = 0; ii < 8; ++ii)
        #pragma unroll
        for (int jj = 0; jj < 6; ++jj) acc[ii][jj] = 0.0f;

    #pragma unroll 4
    for (int k = 0; k < 64; ++k) {
        float xv[8], wvv[6];
        #pragma unroll
        for (int ii = 0; ii < 8; ++ii) xv[ii] = Xs[(i0 + ii) * 64 + k];
        #pragma unroll
        for (int jj = 0; jj < 6; ++jj) wvv[jj] = Wt[widx[jj] + k * 64];
        #pragma unroll
        for (int ii = 0; ii < 8; ++ii)
            #pragma unroll
            for (int jj = 0; jj < 6; ++jj)
                acc[ii][jj] = fmaf(xv[ii], wvv[jj], acc[ii][jj]);
    }

    #pragma unroll
    for (int ii = 0; ii < 8; ++ii) {
        int tokl = tb + i0 + ii;
        unsigned short* dst = qkv + tokl * 192 + j0;
        *(unsigned*)(dst + 0) = pack2(acc[ii][0], acc[ii][1]);
        *(unsigned*)(dst + 2) = pack2(acc[ii][2], acc[ii][3]);
        *(unsigned*)(dst + 4) = pack2(acc[ii][4], acc[ii][5]);
    }
}

// ---------------------------------------------------------------------------
// K1b: per-group attention (16 tokens, head_dim 64), one wave per group.
// Reads qkv bf16, fp32 compute, writes out2 bf16 [16384][1024] in the
// reference's transpose/reshape layout: out2[b*512 + h*32 + g/16][(g%16)*64+d]
// ---------------------------------------------------------------------------
__global__ __launch_bounds__(256) void k_attn(const unsigned short* __restrict__ qkv,
                                              unsigned short* __restrict__ out2) {
    __shared__ float Qs[4][16 * 68];
    __shared__ float Ks[4][16 * 68];
    __shared__ float Vs[4][16 * 68];
    __shared__ float Es[4][16 * 16];
    int t = threadIdx.x;
    int w = t >> 6;
    int l = t & 63;
    int gi = blockIdx.x * 4 + w;
    int b  = gi >> 9;
    int g  = gi & 511;

    // Stage Q,K,V for this group into LDS (fp32)
    int h = l >> 2;
    int cbase = (l & 3) * 48;
    const unsigned short* src = qkv + (gi * 16 + h) * 192 + cbase;
    #pragma unroll
    for (int cc = 0; cc < 6; ++cc) {
        uint4 u = *(const uint4*)(src + cc * 8);
        unsigned vals[4] = {u.x, u.y, u.z, u.w};
        #pragma unroll
        for (int p = 0; p < 4; ++p) {
            int c  = cbase + cc * 8 + p * 2;
            int m  = c >> 6;
            int cl = c & 63;
            float* dst = (m == 0) ? Qs[w] : ((m == 1) ? Ks[w] : Vs[w]);
            dst[h * 68 + cl]     = bf2f((unsigned short)(vals[p] & 0xffff));
            dst[h * 68 + cl + 1] = bf2f((unsigned short)(vals[p] >> 16));
        }
    }
    __syncthreads();

    // energy[i][j] = Q[i] . K[j]
    int i = l >> 2;
    #pragma unroll
    for (int jj = 0; jj < 4; ++jj) {
        int j = (l & 3) * 4 + jj;
        float s = 0.0f;
        #pragma unroll 8
        for (int k = 0; k < 64; ++k)
            s = fmaf(Qs[w][i * 68 + k], Ks[w][j * 68 + k], s);
        Es[w][i * 16 + j] = s;
    }
    __syncthreads();

    // softmax over j, logits scaled by 1/sqrt(1024) = 1/32
    if (l < 16) {
        float* row = &Es[w][l * 16];
        float mx = row[0];
        #pragma unroll
        for (int j = 1; j < 16; ++j) mx = fmaxf(mx, row[j]);
        float p[16];
        float sum = 0.0f;
        #pragma unroll
        for (int j = 0; j < 16; ++j) {
            p[j] = expf((row[j] - mx) * 0.03125f);
            sum += p[j];
        }
        float r = 1.0f / sum;
        #pragma unroll
        for (int j = 0; j < 16; ++j) row[j] = p[j] * r;
    }
    __syncthreads();

    // out[i][d] = sum_j attn[i][j] * V[j][d]
    int dbase = (l & 3) * 16;
    float o[16];
    #pragma unroll
    for (int dd = 0; dd < 16; ++dd) o[dd] = 0.0f;
    #pragma unroll
    for (int j = 0; j < 16; ++j) {
        float a = Es[w][i * 16 + j];
        #pragma unroll
        for (int dd = 0; dd < 16; ++dd)
            o[dd] = fmaf(a, Vs[w][j * 68 + dbase + dd], o[dd]);
    }

    int r2 = b * 512 + i * 32 + (g >> 4);
    unsigned short* dst = out2 + r2 * 1024 + (g & 15) * 64 + dbase;
    uint4 s0, s1;
    s0.x = pack2(o[0], o[1]);   s0.y = pack2(o[2], o[3]);
    s0.z = pack2(o[4], o[5]);   s0.w = pack2(o[6], o[7]);
    s1.x = pack2(o[8], o[9]);   s1.y = pack2(o[10], o[11]);
    s1.z = pack2(o[12], o[13]); s1.w = pack2(o[14], o[15]);
    *(uint4*)(dst)     = s0;
    *(uint4*)(dst + 8) = s1;
}

// ---------------------------------------------------------------------------
// K2: C[16384][1024] = out2 @ Wo^T + bo  (bf16 MFMA, fp32 acc/out)
// 128x128 block tile, BK=32, 256 threads (4 waves, 2x2), 16x16x32 MFMA.
// ---------------------------------------------------------------------------
__global__ __launch_bounds__(256) void k_gemm(const unsigned short* __restrict__ A,
                                              const unsigned short* __restrict__ Bm,
                                              const float* __restrict__ bias,
                                              float* __restrict__ C) {
    __shared__ unsigned short As[128 * 32];
    __shared__ unsigned short Bs[128 * 32];
    const int K = 1024;
    int t  = threadIdx.x;
    int n0 = blockIdx.x * 128;
    int m0 = blockIdx.y * 128;
    int w  = t >> 6;
    int l  = t & 63;
    int wm = (w & 1) * 64;
    int wn = (w >> 1) * 64;
    int lm = l & 15;
    int q4 = l >> 4;

    f32x4 acc[4][4];
    #pragma unroll
    for (int mi = 0; mi < 4; ++mi)
        #pragma unroll
        for (int ni = 0; ni < 4; ++ni)
            acc[mi][ni] = (f32x4){0.f, 0.f, 0.f, 0.f};

    for (int k0 = 0; k0 < K; k0 += 32) {
        #pragma unroll
        for (int q = 0; q < 2; ++q) {
            int lin = q * 256 + t;          // 8 bf16 per slot, lane-ordered LDS
            int row = lin >> 2;
            int kk  = (lin & 3) * 8;
            uint4 av = *(const uint4*)(A + (m0 + row) * K + k0 + kk);
            *(uint4*)(As + lin * 8) = av;
            uint4 bv = *(const uint4*)(Bm + (n0 + row) * K + k0 + kk);
            *(uint4*)(Bs + lin * 8) = bv;
        }
        __syncthreads();

        bf16x8 af[4], bfr[4];
        #pragma unroll
        for (int mi = 0; mi < 4; ++mi)
            af[mi] = *(const bf16x8*)(As + (wm + mi * 16 + lm) * 32 + q4 * 8);
        #pragma unroll
        for (int ni = 0; ni < 4; ++ni)
            bfr[ni] = *(const bf16x8*)(Bs + (wn + ni * 16 + lm) * 32 + q4 * 8);
        #pragma unroll
        for (int mi = 0; mi < 4; ++mi)
            #pragma unroll
            for (int ni = 0; ni < 4; ++ni)
                acc[mi][ni] = __builtin_amdgcn_mfma_f32_16x16x32_bf16(
                    af[mi], bfr[ni], acc[mi][ni], 0, 0, 0);
        __syncthreads();
    }

    #pragma unroll
    for (int mi = 0; mi < 4; ++mi) {
        #pragma unroll
        for (int ni = 0; ni < 4; ++ni) {
            int col = n0 + wn + ni * 16 + lm;
            float bcol = bias[col];
            #pragma unroll
            for (int r = 0; r < 4; ++r) {
                int row = m0 + wm + mi * 16 + q4 * 4 + r;
                C[row * 1024 + col] = acc[mi][ni][r] + bcol;
            }
        }
    }
}

// ---------------------------------------------------------------------------
extern "C" void kernel_launch(void* const* d_in, const int* in_sizes, int n_in,
                              void* d_out, int out_size, void* d_ws, size_t ws_size,
                              hipStream_t stream) {
    const float* x  = (const float*)d_in[0];
    const float* wq = (const float*)d_in[1];
    const float* wk = (const float*)d_in[2];
    const float* wv = (const float*)d_in[3];
    const float* wo = (const float*)d_in[4];
    const float* bo = (const float*)d_in[5];
    float* out = (float*)d_out;

    unsigned short* qkv  = (unsigned short*)d_ws;            // 262144*192 bf16 (96 MB)
    unsigned short* out2 = qkv + (size_t)TOKS * 192;         // 16384*1024 bf16 (32 MB)
    unsigned short* wob  = out2 + (size_t)NGRP * 1024;       // 1024*1024 bf16 (2 MB)

    k_cvt_wo<<<1024, 256, 0, stream>>>(wo, wob);
    k_qkv  <<<4096, 256, 0, stream>>>(x, wq, wk, wv, qkv);
    k_attn <<<4096, 256, 0, stream>>>(qkv, out2);
    k_gemm <<<dim3(8, 128), 256, 0, stream>>>(out2, wob, bo, out);
}

// Round 2
// 214.820 us; speedup vs baseline: 1.5481x; 1.5481x over previous
//
#include <hip/hip_runtime.h>
#include <stdint.h>

// Problem constants
#define TOKS   262144      // B*S = 32*8192
#define NGRP   16384       // B*G = 32*512
#define EMB    1024
#define HD     64

using bf16x8 = __attribute__((ext_vector_type(8))) short;   // 8 bf16 (4 VGPRs) MFMA operand
using f32x4  = __attribute__((ext_vector_type(4))) float;   // MFMA accumulator

__device__ __forceinline__ unsigned short f2bf(float f) {
    unsigned x = __builtin_bit_cast(unsigned, f);
    unsigned r = (x + 0x7fffu + ((x >> 16) & 1u)) >> 16;   // RNE
    return (unsigned short)r;
}
__device__ __forceinline__ unsigned pack2(float a, float b) {
    return (unsigned)f2bf(a) | ((unsigned)f2bf(b) << 16);
}
__device__ __forceinline__ bf16x8 cvt8(float4 v0, float4 v1) {
    uint4 u;
    u.x = pack2(v0.x, v0.y);
    u.y = pack2(v0.z, v0.w);
    u.z = pack2(v1.x, v1.y);
    u.w = pack2(v1.z, v1.w);
    return __builtin_bit_cast(bf16x8, u);
}

// ---------------------------------------------------------------------------
// K0: convert Wo (fp32 [1024][1024]) -> bf16
// ---------------------------------------------------------------------------
__global__ __launch_bounds__(256) void k_cvt_wo(const float* __restrict__ wo,
                                                unsigned short* __restrict__ out) {
    int idx = (blockIdx.x * 256 + threadIdx.x) * 4;
    float4 v = *(const float4*)(wo + idx);
    uint2 p;
    p.x = pack2(v.x, v.y);
    p.y = pack2(v.z, v.w);
    *(uint2*)(out + idx) = p;
}

// ---------------------------------------------------------------------------
// K1: FUSED QKV projection + 16x16 attention, MFMA throughout.
// Block = 256 threads (4 waves). Each wave owns 64 tokens = 4 groups,
// processed in 2 passes of 2 groups. Per-wave-private LDS (no barriers).
//
// Layout algebra (16x16x32 bf16 MFMA, all HW-verified mappings):
//   A-frag: lane(q,c) holds A[m=c][k=8q+j]        (j=0..7)
//   B-frag: lane(q,c) holds B[k=8q+j][n=c]
//   D-frag: lane(q,c) holds D[row=4q+r][col=c]    (r=0..3)
// Projection P = x @ W^T: A = x rows (8 consec fp32), B[k][n]=W[n][k] (8
// consec fp32 of W row n). D: P[tok=4q+r][d=16nb+c].
// energy^T = mfma(A=K-frag, B=Q-frag) after LDS round-trip of Q,K tiles.
// Softmax over j = D rows: in-lane over 4 regs + shfl_xor 16/32.
// PV A-frag (attn[i=c][j]) == softmax result layout, redistributed across
// quads by 4 shuffles (k=8q+jj needs j-blocks 8q..8q+7; quads 2,3 are the
// zero-pad for K=32 vs j<16). PV B-frag (V[j][d]) built from V D-frags by
// shuffles -- V never touches LDS.
// ---------------------------------------------------------------------------
#define SCL 0.0450842200278f   /* log2(e)/32 */

__global__ __launch_bounds__(256) void k_fused(const float* __restrict__ x,
                                               const float* __restrict__ wq,
                                               const float* __restrict__ wk,
                                               const float* __restrict__ wv,
                                               unsigned short* __restrict__ out2) {
    // [wave][group-in-pass][Q/K][16 x 72 bf16]  (pad 64->72 breaks bank aliasing)
    __shared__ __align__(16) unsigned short qkls[4][2][2][16 * 72];
    int t = threadIdx.x;
    int w = t >> 6, l = t & 63;
    int c = l & 15, q = l >> 4;
    int waveTok0 = blockIdx.x * 256 + w * 64;
    const float* Wm[3] = {wq, wk, wv};

    for (int pass = 0; pass < 2; ++pass) {
        int g0 = pass * 2;

        // ---- x A-frags for the 2 groups ----
        bf16x8 xa[2][2];
        #pragma unroll
        for (int g = 0; g < 2; ++g) {
            const float* xp = x + (size_t)(waveTok0 + (g0 + g) * 16 + c) * 64 + q * 8;
            #pragma unroll
            for (int kc = 0; kc < 2; ++kc) {
                float4 v0 = *(const float4*)(xp + kc * 32);
                float4 v1 = *(const float4*)(xp + kc * 32 + 4);
                xa[g][kc] = cvt8(v0, v1);
            }
        }

        // ---- projections ----
        uint2 pkV[2][4];
        #pragma unroll
        for (int m = 0; m < 3; ++m) {
            bf16x8 wb[4][2];
            #pragma unroll
            for (int nb = 0; nb < 4; ++nb) {
                const float* wp = Wm[m] + (nb * 16 + c) * 64 + q * 8;
                #pragma unroll
                for (int kc = 0; kc < 2; ++kc) {
                    float4 v0 = *(const float4*)(wp + kc * 32);
                    float4 v1 = *(const float4*)(wp + kc * 32 + 4);
                    wb[nb][kc] = cvt8(v0, v1);
                }
            }
            #pragma unroll
            for (int g = 0; g < 2; ++g) {
                #pragma unroll
                for (int nb = 0; nb < 4; ++nb) {
                    f32x4 acc = (f32x4){0.f, 0.f, 0.f, 0.f};
                    acc = __builtin_amdgcn_mfma_f32_16x16x32_bf16(xa[g][0], wb[nb][0], acc, 0, 0, 0);
                    acc = __builtin_amdgcn_mfma_f32_16x16x32_bf16(xa[g][1], wb[nb][1], acc, 0, 0, 0);
                    if (m < 2) {
                        unsigned short* tile = qkls[w][g][m];
                        #pragma unroll
                        for (int r = 0; r < 4; ++r)
                            tile[(4 * q + r) * 72 + nb * 16 + c] = f2bf(acc[r]);
                    } else {
                        pkV[g][nb].x = pack2(acc[0], acc[1]);   // tokens 4q+0,1
                        pkV[g][nb].y = pack2(acc[2], acc[3]);   // tokens 4q+2,3
                    }
                }
            }
        }

        // ---- attention per group ----
        #pragma unroll
        for (int g = 0; g < 2; ++g) {
            int gi = (waveTok0 >> 4) + g0 + g;

            // energy^T[j][i]: A = K-frag, B = Q-frag (identical LDS pattern)
            const unsigned short* Qt = qkls[w][g][0];
            const unsigned short* Kt = qkls[w][g][1];
            f32x4 e = (f32x4){0.f, 0.f, 0.f, 0.f};
            #pragma unroll
            for (int kc = 0; kc < 2; ++kc) {
                bf16x8 ka = *(const bf16x8*)(Kt + c * 72 + kc * 32 + q * 8);
                bf16x8 qb = *(const bf16x8*)(Qt + c * 72 + kc * 32 + q * 8);
                e = __builtin_amdgcn_mfma_f32_16x16x32_bf16(ka, qb, e, 0, 0, 0);
            }
            // lane(q,c): e[r] = energy[i=c][j=4q+r]

            // softmax over j (4 regs + cross-quad)
            float mx = fmaxf(fmaxf(e[0], e[1]), fmaxf(e[2], e[3]));
            mx = fmaxf(mx, __shfl_xor(mx, 16));
            mx = fmaxf(mx, __shfl_xor(mx, 32));
            float p0 = exp2f((e[0] - mx) * SCL);
            float p1 = exp2f((e[1] - mx) * SCL);
            float p2 = exp2f((e[2] - mx) * SCL);
            float p3 = exp2f((e[3] - mx) * SCL);
            float s = p0 + p1 + p2 + p3;
            s += __shfl_xor(s, 16);
            s += __shfl_xor(s, 32);
            float rinv = 1.0f / s;

            // PV A-frag: attn[i=c][k=8q+jj]; j-blocks gathered from quads 2q,2q+1
            unsigned pa0 = pack2(p0 * rinv, p1 * rinv);   // j = 4q+0,1
            unsigned pa1 = pack2(p2 * rinv, p3 * rinv);   // j = 4q+2,3
            int s0 = (32 * q + c) & 63;
            int s1 = (32 * q + 16 + c) & 63;
            int a0 = __shfl((int)pa0, s0);
            int a1 = __shfl((int)pa1, s0);
            int a2 = __shfl((int)pa0, s1);
            int a3 = __shfl((int)pa1, s1);
            uint4 A2u;
            bool hi = (q >= 2);                 // k >= 16 -> zero pad
            A2u.x = hi ? 0u : (unsigned)a0;
            A2u.y = hi ? 0u : (unsigned)a1;
            A2u.z = hi ? 0u : (unsigned)a2;
            A2u.w = hi ? 0u : (unsigned)a3;
            bf16x8 A2 = __builtin_bit_cast(bf16x8, A2u);

            // PV per d-chunk: B-frag V[j=8q'+jj][d=16nb+c] via shuffles
            int v0 = 32 * (q & 1) + c;
            int v1 = v0 + 16;
            int b  = gi >> 9;
            int grem = gi & 511;
            int rowbase = b * 512 + (grem >> 4);
            int colpref = (grem & 15) * 64;
            #pragma unroll
            for (int nb = 0; nb < 4; ++nb) {
                uint4 B2u;
                B2u.x = (unsigned)__shfl((int)pkV[g][nb].x, v0);   // tokens 8q'+0,1
                B2u.y = (unsigned)__shfl((int)pkV[g][nb].y, v0);   // tokens 8q'+2,3
                B2u.z = (unsigned)__shfl((int)pkV[g][nb].x, v1);   // tokens 8q'+4,5
                B2u.w = (unsigned)__shfl((int)pkV[g][nb].y, v1);   // tokens 8q'+6,7
                bf16x8 B2 = __builtin_bit_cast(bf16x8, B2u);
                f32x4 o = (f32x4){0.f, 0.f, 0.f, 0.f};
                o = __builtin_amdgcn_mfma_f32_16x16x32_bf16(A2, B2, o, 0, 0, 0);
                // o[r] = out[i=4q+r][d=16nb+c]
                int col = colpref + nb * 16 + c;
                #pragma unroll
                for (int r = 0; r < 4; ++r) {
                    int i = 4 * q + r;
                    out2[(size_t)(rowbase + i * 32) * 1024 + col] = f2bf(o[r]);
                }
            }
        }
    }
}

// ---------------------------------------------------------------------------
// K2: C[16384][1024] = out2 @ Wo^T + bo  (bf16 MFMA, fp32 acc/out)
// 128x128 block tile, BK=32, 256 threads (4 waves, 2x2), 16x16x32 MFMA.
// ---------------------------------------------------------------------------
__global__ __launch_bounds__(256) void k_gemm(const unsigned short* __restrict__ A,
                                              const unsigned short* __restrict__ Bm,
                                              const float* __restrict__ bias,
                                              float* __restrict__ C) {
    __shared__ unsigned short As[128 * 32];
    __shared__ unsigned short Bs[128 * 32];
    const int K = 1024;
    int t  = threadIdx.x;
    int n0 = blockIdx.x * 128;
    int m0 = blockIdx.y * 128;
    int w  = t >> 6;
    int l  = t & 63;
    int wm = (w & 1) * 64;
    int wn = (w >> 1) * 64;
    int lm = l & 15;
    int q4 = l >> 4;

    f32x4 acc[4][4];
    #pragma unroll
    for (int mi = 0; mi < 4; ++mi)
        #pragma unroll
        for (int ni = 0; ni < 4; ++ni)
            acc[mi][ni] = (f32x4){0.f, 0.f, 0.f, 0.f};

    for (int k0 = 0; k0 < K; k0 += 32) {
        #pragma unroll
        for (int q = 0; q < 2; ++q) {
            int lin = q * 256 + t;          // 8 bf16 per slot, lane-ordered LDS
            int row = lin >> 2;
            int kk  = (lin & 3) * 8;
            uint4 av = *(const uint4*)(A + (size_t)(m0 + row) * K + k0 + kk);
            *(uint4*)(As + lin * 8) = av;
            uint4 bv = *(const uint4*)(Bm + (size_t)(n0 + row) * K + k0 + kk);
            *(uint4*)(Bs + lin * 8) = bv;
        }
        __syncthreads();

        bf16x8 af[4], bfr[4];
        #pragma unroll
        for (int mi = 0; mi < 4; ++mi)
            af[mi] = *(const bf16x8*)(As + (wm + mi * 16 + lm) * 32 + q4 * 8);
        #pragma unroll
        for (int ni = 0; ni < 4; ++ni)
            bfr[ni] = *(const bf16x8*)(Bs + (wn + ni * 16 + lm) * 32 + q4 * 8);
        #pragma unroll
        for (int mi = 0; mi < 4; ++mi)
            #pragma unroll
            for (int ni = 0; ni < 4; ++ni)
                acc[mi][ni] = __builtin_amdgcn_mfma_f32_16x16x32_bf16(
                    af[mi], bfr[ni], acc[mi][ni], 0, 0, 0);
        __syncthreads();
    }

    #pragma unroll
    for (int mi = 0; mi < 4; ++mi) {
        #pragma unroll
        for (int ni = 0; ni < 4; ++ni) {
            int col = n0 + wn + ni * 16 + lm;
            float bcol = bias[col];
            #pragma unroll
            for (int r = 0; r < 4; ++r) {
                int row = m0 + wm + mi * 16 + q4 * 4 + r;
                C[(size_t)row * 1024 + col] = acc[mi][ni][r] + bcol;
            }
        }
    }
}

// ---------------------------------------------------------------------------
extern "C" void kernel_launch(void* const* d_in, const int* in_sizes, int n_in,
                              void* d_out, int out_size, void* d_ws, size_t ws_size,
                              hipStream_t stream) {
    const float* x  = (const float*)d_in[0];
    const float* wq = (const float*)d_in[1];
    const float* wk = (const float*)d_in[2];
    const float* wv = (const float*)d_in[3];
    const float* wo = (const float*)d_in[4];
    const float* bo = (const float*)d_in[5];
    float* out = (float*)d_out;

    unsigned short* out2 = (unsigned short*)d_ws;            // 16384*1024 bf16 (32 MB)
    unsigned short* wob  = out2 + (size_t)NGRP * 1024;       // 1024*1024 bf16 (2 MB)

    k_cvt_wo<<<1024, 256, 0, stream>>>(wo, wob);
    k_fused<<<1024, 256, 0, stream>>>(x, wq, wk, wv, out2);
    k_gemm <<<dim3(8, 128), 256, 0, stream>>>(out2, wob, bo, out);
}

// Round 3
// 193.728 us; speedup vs baseline: 1.7167x; 1.1089x over previous
//
#include <hip/hip_runtime.h>
#include <stdint.h>

// Problem constants
#define TOKS   262144      // B*S = 32*8192
#define NGRP   16384       // B*G = 32*512
#define EMB    1024
#define HD     64

using bf16x8 = __attribute__((ext_vector_type(8))) short;   // 8 bf16 (4 VGPRs) MFMA operand
using f32x4  = __attribute__((ext_vector_type(4))) float;   // MFMA accumulator

__device__ __forceinline__ unsigned short f2bf(float f) {
    unsigned x = __builtin_bit_cast(unsigned, f);
    unsigned r = (x + 0x7fffu + ((x >> 16) & 1u)) >> 16;   // RNE
    return (unsigned short)r;
}
__device__ __forceinline__ unsigned pack2(float a, float b) {
    return (unsigned)f2bf(a) | ((unsigned)f2bf(b) << 16);
}
__device__ __forceinline__ bf16x8 cvt8(float4 v0, float4 v1) {
    uint4 u;
    u.x = pack2(v0.x, v0.y);
    u.y = pack2(v0.z, v0.w);
    u.z = pack2(v1.x, v1.y);
    u.w = pack2(v1.z, v1.w);
    return __builtin_bit_cast(bf16x8, u);
}
__device__ __forceinline__ void gload_lds16(const unsigned short* g, unsigned short* l) {
    __builtin_amdgcn_global_load_lds(
        (const __attribute__((address_space(1))) void*)g,
        (__attribute__((address_space(3))) void*)l,
        16, 0, 0);
}

// ---------------------------------------------------------------------------
// K0a: convert Wo (fp32 [1024][1024]) -> bf16
// ---------------------------------------------------------------------------
__global__ __launch_bounds__(256) void k_cvt_wo(const float* __restrict__ wo,
                                                unsigned short* __restrict__ out) {
    int idx = (blockIdx.x * 256 + threadIdx.x) * 4;
    float4 v = *(const float4*)(wo + idx);
    uint2 p;
    p.x = pack2(v.x, v.y);
    p.y = pack2(v.z, v.w);
    *(uint2*)(out + idx) = p;
}

// K0b: convert Wq|Wk|Wv (each fp32 [64][64]) -> bf16, packed [3][4096]
__global__ __launch_bounds__(256) void k_cvt_w3(const float* __restrict__ wq,
                                                const float* __restrict__ wk,
                                                const float* __restrict__ wv,
                                                unsigned short* __restrict__ dst) {
    int b = blockIdx.x;                 // 0..11
    int m = b >> 2;
    const float* src = (m == 0) ? wq : ((m == 1) ? wk : wv);
    int idx = ((b & 3) * 256 + threadIdx.x) * 4;
    float4 v = *(const float4*)(src + idx);
    uint2 p;
    p.x = pack2(v.x, v.y);
    p.y = pack2(v.z, v.w);
    *(uint2*)(dst + m * 4096 + idx) = p;
}

// ---------------------------------------------------------------------------
// K1: FUSED QKV projection + 16x16 attention, MFMA throughout.
// Block = 256 threads (4 waves). Each wave owns 64 tokens = 4 groups,
// processed in 2 passes of 2 groups. Per-wave-private LDS (no barriers).
// W is pre-converted bf16 and read straight into B-frag layout (16 B/lane).
// ---------------------------------------------------------------------------
#define SCL 0.0450842200278f   /* log2(e)/32 */

__global__ __launch_bounds__(256) void k_fused(const float* __restrict__ x,
                                               const unsigned short* __restrict__ wqkv,
                                               unsigned short* __restrict__ out2) {
    // [wave][group-in-pass][Q/K][16 x 72 bf16]  (pad 64->72 breaks bank aliasing)
    __shared__ __align__(16) unsigned short qkls[4][2][2][16 * 72];
    int t = threadIdx.x;
    int w = t >> 6, l = t & 63;
    int c = l & 15, q = l >> 4;
    int waveTok0 = blockIdx.x * 256 + w * 64;

    for (int pass = 0; pass < 2; ++pass) {
        int g0 = pass * 2;

        // ---- x A-frags for the 2 groups (fp32 -> bf16 in-register) ----
        bf16x8 xa[2][2];
        #pragma unroll
        for (int g = 0; g < 2; ++g) {
            const float* xp = x + (size_t)(waveTok0 + (g0 + g) * 16 + c) * 64 + q * 8;
            #pragma unroll
            for (int kc = 0; kc < 2; ++kc) {
                float4 v0 = *(const float4*)(xp + kc * 32);
                float4 v1 = *(const float4*)(xp + kc * 32 + 4);
                xa[g][kc] = cvt8(v0, v1);
            }
        }

        // ---- projections ----
        uint2 pkV[2][4];
        #pragma unroll
        for (int m = 0; m < 3; ++m) {
            bf16x8 wb[4][2];
            #pragma unroll
            for (int nb = 0; nb < 4; ++nb) {
                const unsigned short* wp = wqkv + m * 4096 + (nb * 16 + c) * 64 + q * 8;
                wb[nb][0] = *(const bf16x8*)(wp);
                wb[nb][1] = *(const bf16x8*)(wp + 32);
            }
            #pragma unroll
            for (int g = 0; g < 2; ++g) {
                #pragma unroll
                for (int nb = 0; nb < 4; ++nb) {
                    f32x4 acc = (f32x4){0.f, 0.f, 0.f, 0.f};
                    acc = __builtin_amdgcn_mfma_f32_16x16x32_bf16(xa[g][0], wb[nb][0], acc, 0, 0, 0);
                    acc = __builtin_amdgcn_mfma_f32_16x16x32_bf16(xa[g][1], wb[nb][1], acc, 0, 0, 0);
                    if (m < 2) {
                        unsigned short* tile = qkls[w][g][m];
                        #pragma unroll
                        for (int r = 0; r < 4; ++r)
                            tile[(4 * q + r) * 72 + nb * 16 + c] = f2bf(acc[r]);
                    } else {
                        pkV[g][nb].x = pack2(acc[0], acc[1]);   // tokens 4q+0,1
                        pkV[g][nb].y = pack2(acc[2], acc[3]);   // tokens 4q+2,3
                    }
                }
            }
        }

        // ---- attention per group ----
        #pragma unroll
        for (int g = 0; g < 2; ++g) {
            int gi = (waveTok0 >> 4) + g0 + g;

            // energy^T[j][i]: A = K-frag, B = Q-frag
            const unsigned short* Qt = qkls[w][g][0];
            const unsigned short* Kt = qkls[w][g][1];
            f32x4 e = (f32x4){0.f, 0.f, 0.f, 0.f};
            #pragma unroll
            for (int kc = 0; kc < 2; ++kc) {
                bf16x8 ka = *(const bf16x8*)(Kt + c * 72 + kc * 32 + q * 8);
                bf16x8 qb = *(const bf16x8*)(Qt + c * 72 + kc * 32 + q * 8);
                e = __builtin_amdgcn_mfma_f32_16x16x32_bf16(ka, qb, e, 0, 0, 0);
            }
            // lane(q,c): e[r] = energy[i=c][j=4q+r]

            // softmax over j (4 regs + cross-quad)
            float mx = fmaxf(fmaxf(e[0], e[1]), fmaxf(e[2], e[3]));
            mx = fmaxf(mx, __shfl_xor(mx, 16));
            mx = fmaxf(mx, __shfl_xor(mx, 32));
            float p0 = exp2f((e[0] - mx) * SCL);
            float p1 = exp2f((e[1] - mx) * SCL);
            float p2 = exp2f((e[2] - mx) * SCL);
            float p3 = exp2f((e[3] - mx) * SCL);
            float s = p0 + p1 + p2 + p3;
            s += __shfl_xor(s, 16);
            s += __shfl_xor(s, 32);
            float rinv = 1.0f / s;

            // PV A-frag: attn[i=c][k=8q+jj]; j-blocks gathered from quads 2q,2q+1
            unsigned pa0 = pack2(p0 * rinv, p1 * rinv);   // j = 4q+0,1
            unsigned pa1 = pack2(p2 * rinv, p3 * rinv);   // j = 4q+2,3
            int s0 = (32 * q + c) & 63;
            int s1 = (32 * q + 16 + c) & 63;
            int a0 = __shfl((int)pa0, s0);
            int a1 = __shfl((int)pa1, s0);
            int a2 = __shfl((int)pa0, s1);
            int a3 = __shfl((int)pa1, s1);
            uint4 A2u;
            bool hi = (q >= 2);                 // k >= 16 -> zero pad
            A2u.x = hi ? 0u : (unsigned)a0;
            A2u.y = hi ? 0u : (unsigned)a1;
            A2u.z = hi ? 0u : (unsigned)a2;
            A2u.w = hi ? 0u : (unsigned)a3;
            bf16x8 A2 = __builtin_bit_cast(bf16x8, A2u);

            // PV per d-chunk: B-frag V[j=8q'+jj][d=16nb+c] via shuffles
            int v0 = 32 * (q & 1) + c;
            int v1 = v0 + 16;
            int b  = gi >> 9;
            int grem = gi & 511;
            int rowbase = b * 512 + (grem >> 4);
            int colpref = (grem & 15) * 64;
            #pragma unroll
            for (int nb = 0; nb < 4; ++nb) {
                uint4 B2u;
                B2u.x = (unsigned)__shfl((int)pkV[g][nb].x, v0);   // tokens 8q'+0,1
                B2u.y = (unsigned)__shfl((int)pkV[g][nb].y, v0);   // tokens 8q'+2,3
                B2u.z = (unsigned)__shfl((int)pkV[g][nb].x, v1);   // tokens 8q'+4,5
                B2u.w = (unsigned)__shfl((int)pkV[g][nb].y, v1);   // tokens 8q'+6,7
                bf16x8 B2 = __builtin_bit_cast(bf16x8, B2u);
                f32x4 o = (f32x4){0.f, 0.f, 0.f, 0.f};
                o = __builtin_amdgcn_mfma_f32_16x16x32_bf16(A2, B2, o, 0, 0, 0);
                // o[r] = out[i=4q+r][d=16nb+c]
                int col = colpref + nb * 16 + c;
                #pragma unroll
                for (int r = 0; r < 4; ++r) {
                    int i = 4 * q + r;
                    out2[(size_t)(rowbase + i * 32) * 1024 + col] = f2bf(o[r]);
                }
            }
        }
    }
}

// ---------------------------------------------------------------------------
// K2: C[16384][1024] = out2 @ Wo^T + bo  (bf16 MFMA, fp32 acc/out)
// 128x128 tile, BK=32, 256 threads (4 waves, 2x2), 16x16x32 MFMA.
// m97 recipe: global_load_lds width-16 async staging.
// 1D grid, band-major: m = id & 127 -> all 8 n-tiles of one A-band share
// id%8 (assumed XCD round-robin) -> band fetched once into that XCD's L2.
// ---------------------------------------------------------------------------
__global__ __launch_bounds__(256) void k_gemm(const unsigned short* __restrict__ A,
                                              const unsigned short* __restrict__ Bm,
                                              const float* __restrict__ bias,
                                              float* __restrict__ C) {
    __shared__ __align__(16) unsigned short As[128 * 32];
    __shared__ __align__(16) unsigned short Bs[128 * 32];
    const int K = 1024;
    int t  = threadIdx.x;
    int id = blockIdx.x;
    int m0 = (id & 127) * 128;
    int n0 = (id >> 7) * 128;
    int w  = t >> 6;
    int l  = t & 63;
    int wm = (w & 1) * 64;
    int wn = (w >> 1) * 64;
    int lm = l & 15;
    int q4 = l >> 4;

    // staging descriptors: slot lin -> LDS shorts [lin*8 .. lin*8+8),
    // global row = lin>>2, k-offset = (lin&3)*8.  Per wave the LDS dest is
    // wave-uniform base + lane*16 B (global_load_lds requirement).
    int row0 = t >> 2, kk0 = (t & 3) * 8;          // lin = t
    int row1 = row0 + 64;                          // lin = t + 256, same kk

    f32x4 acc[4][4];
    #pragma unroll
    for (int mi = 0; mi < 4; ++mi)
        #pragma unroll
        for (int ni = 0; ni < 4; ++ni)
            acc[mi][ni] = (f32x4){0.f, 0.f, 0.f, 0.f};

    const unsigned short* Arow0 = A + (size_t)(m0 + row0) * K + kk0;
    const unsigned short* Arow1 = A + (size_t)(m0 + row1) * K + kk0;
    const unsigned short* Brow0 = Bm + (size_t)(n0 + row0) * K + kk0;
    const unsigned short* Brow1 = Bm + (size_t)(n0 + row1) * K + kk0;

    for (int k0 = 0; k0 < K; k0 += 32) {
        gload_lds16(Arow0 + k0, As + (size_t)t * 8);
        gload_lds16(Arow1 + k0, As + (size_t)(t + 256) * 8);
        gload_lds16(Brow0 + k0, Bs + (size_t)t * 8);
        gload_lds16(Brow1 + k0, Bs + (size_t)(t + 256) * 8);
        __syncthreads();

        bf16x8 af[4], bfr[4];
        #pragma unroll
        for (int mi = 0; mi < 4; ++mi)
            af[mi] = *(const bf16x8*)(As + (wm + mi * 16 + lm) * 32 + q4 * 8);
        #pragma unroll
        for (int ni = 0; ni < 4; ++ni)
            bfr[ni] = *(const bf16x8*)(Bs + (wn + ni * 16 + lm) * 32 + q4 * 8);
        #pragma unroll
        for (int mi = 0; mi < 4; ++mi)
            #pragma unroll
            for (int ni = 0; ni < 4; ++ni)
                acc[mi][ni] = __builtin_amdgcn_mfma_f32_16x16x32_bf16(
                    af[mi], bfr[ni], acc[mi][ni], 0, 0, 0);
        __syncthreads();
    }

    #pragma unroll
    for (int mi = 0; mi < 4; ++mi) {
        #pragma unroll
        for (int ni = 0; ni < 4; ++ni) {
            int col = n0 + wn + ni * 16 + lm;
            float bcol = bias[col];
            #pragma unroll
            for (int r = 0; r < 4; ++r) {
                int row = m0 + wm + mi * 16 + q4 * 4 + r;
                C[(size_t)row * 1024 + col] = acc[mi][ni][r] + bcol;
            }
        }
    }
}

// ---------------------------------------------------------------------------
extern "C" void kernel_launch(void* const* d_in, const int* in_sizes, int n_in,
                              void* d_out, int out_size, void* d_ws, size_t ws_size,
                              hipStream_t stream) {
    const float* x  = (const float*)d_in[0];
    const float* wq = (const float*)d_in[1];
    const float* wk = (const float*)d_in[2];
    const float* wv = (const float*)d_in[3];
    const float* wo = (const float*)d_in[4];
    const float* bo = (const float*)d_in[5];
    float* out = (float*)d_out;

    unsigned short* out2  = (unsigned short*)d_ws;           // 16384*1024 bf16 (32 MB)
    unsigned short* wob   = out2 + (size_t)NGRP * 1024;      // 1024*1024 bf16 (2 MB)
    unsigned short* wqkvb = wob + (size_t)EMB * EMB;         // 3*4096 bf16 (24 KB)

    k_cvt_wo<<<1024, 256, 0, stream>>>(wo, wob);
    k_cvt_w3<<<12,   256, 0, stream>>>(wq, wk, wv, wqkvb);
    k_fused<<<1024, 256, 0, stream>>>(x, wqkvb, out2);
    k_gemm <<<1024, 256, 0, stream>>>(out2, wob, bo, out);
}